// Round 1
// baseline (259.699 us; speedup 1.0000x reference)
//
#include <hip/hip_runtime.h>
#include <math.h>

// Fused 3-layer MLP: h1 = relu(x@W1^T+b1) [B,3]; h2 = relu(h1@W2^T+b2) [B,2];
// out = sigmoid(h2@W3^T+b3) [B].  All fp32.  Memory-bound: 32 B/row traffic
// (8 B read + 24 B write), 256 MiB total at B=8.39M -> ~41 us floor @6.3 TB/s.
//
// R1/R2 (prev session): LDS-stage outputs per block, drain with fully
// lane-contiguous float4 stores (direct stores were lane-strided, 3x
// transactions).
// R3 (this round), three bundled changes:
//   1. nt stores -> PLAIN vector stores. The harness fill sustains 6.5 TB/s
//      with plain stores; nt (evict-first) was never isolated and is the
//      prime suspect for the ~2.1 TB/s effective kernel BW.
//   2. RPB 1024 -> 512: LDS 24 KB -> 12 KB, occupancy 6 -> 8 blocks/CU
//      (24 -> 32 waves/CU) to smooth the bursty two-phase read/write mix.
//   3. Vectorized, bank-conflict-free LDS writes: per thread (2 rows)
//      3x b64 (h1) + 1x b128 (h2) + 1x b64 (out) instead of 12 scalar
//      ds_write_b32 at word strides 6/4/2 (which alias 4-8-way).
//   Also: sigmoid via v_rcp_f32 instead of the IEEE div sequence.

#define RPB 512  // rows per block (256 threads x 2 rows)

typedef float v4f __attribute__((ext_vector_type(4)));
typedef float v2f __attribute__((ext_vector_type(2)));

__global__ __launch_bounds__(256) void mlp321_kernel(
    const float* __restrict__ x,
    const float* __restrict__ W1, const float* __restrict__ b1,
    const float* __restrict__ W2, const float* __restrict__ b2,
    const float* __restrict__ W3, const float* __restrict__ b3,
    float* __restrict__ out_p, float* __restrict__ h1_p, float* __restrict__ h2_p,
    int nrows)
{
    __shared__ __align__(16) float s_h1[RPB * 3];  // 6 KB
    __shared__ __align__(16) float s_h2[RPB * 2];  // 4 KB
    __shared__ __align__(16) float s_out[RPB];     // 2 KB

    const int tid = threadIdx.x;
    const size_t base = (size_t)blockIdx.x * RPB;

    // Weights: tiny, uniform -> scalar loads / cache broadcast.
    float w1[6], w2[6], w3v[2], bb1[3], bb2[2], bb3;
#pragma unroll
    for (int i = 0; i < 6; ++i) w1[i] = W1[i];
#pragma unroll
    for (int i = 0; i < 3; ++i) bb1[i] = b1[i];
#pragma unroll
    for (int i = 0; i < 6; ++i) w2[i] = W2[i];
#pragma unroll
    for (int i = 0; i < 2; ++i) bb2[i] = b2[i];
    w3v[0] = W3[0]; w3v[1] = W3[1];
    bb3 = b3[0];

    const bool full = (base + RPB) <= (size_t)nrows;  // uniform per block

    if (full) {
        // ---- compute phase: one lane-contiguous float4 x-load = 2 rows ----
        const v4f* xv = reinterpret_cast<const v4f*>(x + base * 2);  // 256 v4f
        v4f xa = xv[tid];
        const float xr[2][2] = {{xa.x, xa.y}, {xa.z, xa.w}};
        float h1v[2][3], h2v[2][2], ov[2];
#pragma unroll
        for (int r = 0; r < 2; ++r) {
            const float x0 = xr[r][0], x1 = xr[r][1];
#pragma unroll
            for (int j = 0; j < 3; ++j) {
                float v = fmaf(x0, w1[j * 2 + 0], fmaf(x1, w1[j * 2 + 1], bb1[j]));
                h1v[r][j] = v > 0.f ? v : 0.f;
            }
#pragma unroll
            for (int k = 0; k < 2; ++k) {
                float v = bb2[k];
#pragma unroll
                for (int j = 0; j < 3; ++j) v = fmaf(h1v[r][j], w2[k * 3 + j], v);
                h2v[r][k] = v > 0.f ? v : 0.f;
            }
            const float z = fmaf(h2v[r][0], w3v[0], fmaf(h2v[r][1], w3v[1], bb3));
            ov[r] = __builtin_amdgcn_rcpf(1.f + __expf(-z));
        }

        // Vectorized LDS writes, conflict-free per 16-lane phase:
        // h1: 3x b64 at word 6*tid (24B-stride, 8B-aligned)
        v2f* h1w = reinterpret_cast<v2f*>(&s_h1[6 * tid]);
        h1w[0] = (v2f){h1v[0][0], h1v[0][1]};
        h1w[1] = (v2f){h1v[0][2], h1v[1][0]};
        h1w[2] = (v2f){h1v[1][1], h1v[1][2]};
        // h2: 1x b128 at word 4*tid (16B-aligned, lanes cover all banks)
        *reinterpret_cast<v4f*>(&s_h2[4 * tid]) =
            (v4f){h2v[0][0], h2v[0][1], h2v[1][0], h2v[1][1]};
        // out: 1x b64 at word 2*tid
        *reinterpret_cast<v2f*>(&s_out[2 * tid]) = (v2f){ov[0], ov[1]};

        __syncthreads();

        // ---- drain phase: fully coalesced PLAIN float4 stores ----
        // v4f counts: s_h1=384, s_h2=256, s_out=128 -> 768 total = 3/thread.
        const v4f* so = reinterpret_cast<const v4f*>(s_out);
        const v4f* s1 = reinterpret_cast<const v4f*>(s_h1);
        const v4f* s2 = reinterpret_cast<const v4f*>(s_h2);
        v4f* po = reinterpret_cast<v4f*>(out_p + base);       // 128 v4f
        v4f* p1 = reinterpret_cast<v4f*>(h1_p + base * 3);    // 384 v4f
        v4f* p2 = reinterpret_cast<v4f*>(h2_p + base * 2);    // 256 v4f

        p1[tid] = s1[tid];
        p2[tid] = s2[tid];
        if (tid < 128) {
            p1[256 + tid] = s1[256 + tid];
        } else {
            po[tid - 128] = so[tid - 128];
        }
    } else {
        // tail block (never taken at B % 512 == 0): scalar guarded path,
        // computed and stored directly, no LDS needed.
        const int remain = (int)((size_t)nrows - base);
        for (int r = tid; r < remain; r += 256) {
            const size_t row = base + r;
            const float x0 = x[row * 2 + 0], x1 = x[row * 2 + 1];
            float h1v[3];
#pragma unroll
            for (int j = 0; j < 3; ++j) {
                float v = fmaf(x0, w1[j * 2 + 0], fmaf(x1, w1[j * 2 + 1], bb1[j]));
                h1v[j] = v > 0.f ? v : 0.f;
                h1_p[row * 3 + j] = h1v[j];
            }
            float h2v[2];
#pragma unroll
            for (int k = 0; k < 2; ++k) {
                float v = bb2[k];
#pragma unroll
                for (int j = 0; j < 3; ++j) v = fmaf(h1v[j], w2[k * 3 + j], v);
                h2v[k] = v > 0.f ? v : 0.f;
                h2_p[row * 2 + k] = h2v[k];
            }
            const float z = fmaf(h2v[0], w3v[0], fmaf(h2v[1], w3v[1], bb3));
            out_p[row] = __builtin_amdgcn_rcpf(1.f + __expf(-z));
        }
    }
}

extern "C" void kernel_launch(void* const* d_in, const int* in_sizes, int n_in,
                              void* d_out, int out_size, void* d_ws, size_t ws_size,
                              hipStream_t stream) {
    const float* x  = (const float*)d_in[0];
    const float* W1 = (const float*)d_in[1];
    const float* b1 = (const float*)d_in[2];
    const float* W2 = (const float*)d_in[3];
    const float* b2 = (const float*)d_in[4];
    const float* W3 = (const float*)d_in[5];
    const float* b3 = (const float*)d_in[6];

    const int B = in_sizes[0] / 2;  // x is [B, 2]
    float* out_p = (float*)d_out;          // [B]
    float* h1_p  = out_p + (size_t)B;      // [B,3]
    float* h2_p  = h1_p + (size_t)B * 3;   // [B,2]

    const int blocks = (B + RPB - 1) / RPB;
    mlp321_kernel<<<blocks, 256, 0, stream>>>(x, W1, b1, W2, b2, W3, b3,
                                              out_p, h1_p, h2_p, B);
}